// Round 7
// baseline (147.130 us; speedup 1.0000x reference)
//
#include <hip/hip_runtime.h>
#include <hip/hip_bf16.h>

#ifndef __has_builtin
#define __has_builtin(x) 0
#endif

__device__ __forceinline__ float fast_exp2(float x) {
#if __has_builtin(__builtin_amdgcn_exp2f)
  return __builtin_amdgcn_exp2f(x);
#else
  return exp2f(x);
#endif
}
__device__ __forceinline__ float fast_rcp(float x) {
#if __has_builtin(__builtin_amdgcn_rcpf)
  return __builtin_amdgcn_rcpf(x);
#else
  return 1.0f / x;
#endif
}

constexpr int Bsz = 8, QL = 128, KL = 512, DD = 256, UU = 256;
constexpr int PR = 8;                    // rows per proj block
constexpr int DT = 8;                    // d-chunk in proj pipeline
constexpr int SQB = 8;                   // q rows per scores block
constexpr int SKB = 128;                 // k cols per scores block (32/wave)
constexpr int QPS = 12;                  // qp_s row stride (16B-aligned, !=0 mod 32)
constexpr float NEG_INF = -1e6f;
constexpr float C2 = 2.885390081777927f; // 2*log2(e): exp2(C2*x) == exp(2x)

// ---------------------------------------------------------------------------
// Kernel 1: projections, pre-scaled by C2, BOTH outputs in natural layout:
//   qp [b][q][u], kpN[b][k][u]  -> all stores coalesced (lane = u).
// thread = u; 8 rows/block; W coalesced + double-buffer prefetched; row
// loads wave-uniform. Fully-masked key blocks exit early.
// ---------------------------------------------------------------------------
__global__ __launch_bounds__(256) void proj_kernel(
    const float* __restrict__ query, const float* __restrict__ key,
    const float* __restrict__ Wq, const float* __restrict__ Wk,
    const int* __restrict__ valid_len,
    float* __restrict__ qp, float* __restrict__ kpN)
{
  const int u   = threadIdx.x;
  const int blk = blockIdx.x;
  constexpr int QBLKS = Bsz * QL / PR;   // 128
  const bool isQ = blk < QBLKS;
  const int  m0  = isQ ? blk * PR : (blk - QBLKS) * PR;

  if (!isQ) {
    const int b = m0 / KL, k0 = m0 % KL;
    if (k0 >= valid_len[b]) return;      // masked rows never read downstream
  }
  const float* __restrict__ in = isQ ? query : key;
  const float* __restrict__ W  = isQ ? Wq : Wk;
  const float* r0 = in + (size_t)m0 * DD;

  float acc[PR];
#pragma unroll
  for (int r = 0; r < PR; ++r) acc[r] = 0.f;

  float w_c[DT], w_n[DT];
#pragma unroll
  for (int j = 0; j < DT; ++j) w_c[j] = W[j * UU + u];

  for (int d = 0; d < DD; d += DT) {
    const int dn = (d + DT < DD) ? d + DT : 0;
#pragma unroll
    for (int j = 0; j < DT; ++j) w_n[j] = W[(dn + j) * UU + u];  // in flight
#pragma unroll
    for (int r = 0; r < PR; ++r) {
      const float4 ra = *reinterpret_cast<const float4*>(r0 + r * DD + d);
      const float4 rb = *reinterpret_cast<const float4*>(r0 + r * DD + d + 4);
      float a = acc[r];
      a = fmaf(ra.x, w_c[0], a);
      a = fmaf(ra.y, w_c[1], a);
      a = fmaf(ra.z, w_c[2], a);
      a = fmaf(ra.w, w_c[3], a);
      a = fmaf(rb.x, w_c[4], a);
      a = fmaf(rb.y, w_c[5], a);
      a = fmaf(rb.z, w_c[6], a);
      a = fmaf(rb.w, w_c[7], a);
      acc[r] = a;
    }
#pragma unroll
    for (int j = 0; j < DT; ++j) w_c[j] = w_n[j];
  }

  float* o = (isQ ? qp : kpN) + (size_t)m0 * UU + u;   // natural [row][u]
#pragma unroll
  for (int r = 0; r < PR; ++r) o[(size_t)r * UU] = acc[r] * C2;
}

// ---------------------------------------------------------------------------
// Kernel 2: scores tile (b, 8q, 128k), trans-dense & single-barrier.
// 512 blocks, 256 threads. Wave w owns the 32-k strip [k0+32w, k0+32w+32);
// lane = (kk = l&31, qh = l>>5): 1 k x 4 q rows per lane. kpN is [b][k][u]:
// lane reads ITS k-column's u-run (2x float4 per 8-u tile, prefetched one
// tile ahead). qp staged in LDS as qp_s[u][q] (stride 12: in-loop b128
// broadcast reads, no in-loop conflicts). Per u: 1 ds_b128 + 1 ds_b32 +
// 4 add + 4 exp + 4 rcp + 4 fma -> 8 trans per ~10 full-rate insts.
// Fully-masked strips return after the single barrier.
// sc[b][q][k] = -sum_u 2*v_w[u]*rcp(1+exp2(qp+kp))  (shift-invariant const
// dropped). Masked sc entries are never read downstream.
// ---------------------------------------------------------------------------
__global__ __launch_bounds__(256) void scores_kernel(
    const int* __restrict__ valid_len, const float* __restrict__ v_w,
    const float* __restrict__ qp, const float* __restrict__ kpN,
    float* __restrict__ sc)
{
  __shared__ __align__(16) float qp_s[UU * QPS];  // 12 KB [u][q], stride 12
  __shared__ float w2_s[UU];                      // 1 KB

  const int t   = threadIdx.x;
  const int blk = blockIdx.x;
  const int b   = blk & 7;                 // batch fastest: mixed vlen per CU
  const int qt  = (blk >> 3) & 15;
  const int kt  = blk >> 7;                // 0..3
  const int q0  = qt * SQB, k0 = kt * SKB;
  const int vlen = valid_len[b];

  // stage 2*v_w and qp tile (8q x 256u) transposed to qp_s[u][q].
  // one-time scattered LDS writes (conflicts amortized over the 256-u loop).
  w2_s[t] = 2.0f * v_w[t];
  {
    const int q_r = t >> 5;               // 0..7
    const int u8  = (t & 31) * 8;         // 0..248
    const float* qrow = qp + ((size_t)(b * QL + q0 + q_r)) * UU + u8;
    const float4 qa = *reinterpret_cast<const float4*>(qrow);
    const float4 qb = *reinterpret_cast<const float4*>(qrow + 4);
    qp_s[(u8 + 0) * QPS + q_r] = qa.x;
    qp_s[(u8 + 1) * QPS + q_r] = qa.y;
    qp_s[(u8 + 2) * QPS + q_r] = qa.z;
    qp_s[(u8 + 3) * QPS + q_r] = qa.w;
    qp_s[(u8 + 4) * QPS + q_r] = qb.x;
    qp_s[(u8 + 5) * QPS + q_r] = qb.y;
    qp_s[(u8 + 6) * QPS + q_r] = qb.z;
    qp_s[(u8 + 7) * QPS + q_r] = qb.w;
  }
  __syncthreads();

  const int w  = t >> 6, l = t & 63;
  const int kk = l & 31, qh = l >> 5;      // k-in-strip, q-half (4 rows each)
  const int kw = k0 + 32 * w;              // wave's k base
  if (kw >= vlen) return;                  // fully-masked strip: sc unread

  const float* __restrict__ kcol = kpN + ((size_t)(b * KL) + kw + kk) * UU;

  float acc0 = 0.f, acc1 = 0.f, acc2 = 0.f, acc3 = 0.f;
  float cur[8], nxt[8];
  *reinterpret_cast<float4*>(&cur[0]) = *reinterpret_cast<const float4*>(kcol);
  *reinterpret_cast<float4*>(&cur[4]) = *reinterpret_cast<const float4*>(kcol + 4);

  for (int u0 = 0; u0 < UU; u0 += 8) {
    if (u0 + 8 < UU) {
      *reinterpret_cast<float4*>(&nxt[0]) =
          *reinterpret_cast<const float4*>(kcol + u0 + 8);
      *reinterpret_cast<float4*>(&nxt[4]) =
          *reinterpret_cast<const float4*>(kcol + u0 + 12);
    }
#pragma unroll
    for (int j = 0; j < 8; ++j) {
      const float  w2 = w2_s[u0 + j];
      const float4 qv =
          *reinterpret_cast<const float4*>(&qp_s[(u0 + j) * QPS + 4 * qh]);
      const float  kv = cur[j];
      const float e0 = fast_exp2(qv.x + kv);
      const float e1 = fast_exp2(qv.y + kv);
      const float e2 = fast_exp2(qv.z + kv);
      const float e3 = fast_exp2(qv.w + kv);
      acc0 = fmaf(w2, fast_rcp(1.0f + e0), acc0);
      acc1 = fmaf(w2, fast_rcp(1.0f + e1), acc1);
      acc2 = fmaf(w2, fast_rcp(1.0f + e2), acc2);
      acc3 = fmaf(w2, fast_rcp(1.0f + e3), acc3);
    }
#pragma unroll
    for (int j = 0; j < 8; ++j) cur[j] = nxt[j];
  }

  // store 4 rows; a q-half's 32 lanes write 32 consecutive floats (coalesced)
  float* srow = sc + ((size_t)(b * QL) + q0 + 4 * qh) * KL + kw + kk;
  srow[0]      = -acc0;
  srow[KL]     = -acc1;
  srow[2 * KL] = -acc2;
  srow[3 * KL] = -acc3;
}

// ---------------------------------------------------------------------------
// Kernel 3: masked softmax over k + attn@value for tile (b, 8q, 128d).
// 256 blocks; 256 threads. Wave w softmaxes rows {2w,2w+1} (masked k ->
// NEG_INF at load; p_s beyond vlen is exactly 0). PV: 16-k chunks, ping-pong
// buffers (no register rotate), value loads coalesced; p_s reads broadcast.
// ---------------------------------------------------------------------------
__global__ __launch_bounds__(256) void softmax_pv_kernel(
    const float* __restrict__ value, const int* __restrict__ valid_len,
    const float* __restrict__ sc, float* __restrict__ out)
{
  __shared__ __align__(16) float p_s[SQB][KL];   // 16 KB attn weights

  const int t = threadIdx.x;
  const int l = t & 63, w = t >> 6;
  const int blk = blockIdx.x;
  const int b  = blk & 7;
  const int qt = (blk >> 3) & 15;
  const int dh = blk >> 7;
  const int q0 = qt * SQB;
  const int d0 = dh * 128;
  const int vlen = valid_len[b];

#pragma unroll
  for (int r = 0; r < 2; ++r) {
    const int row = 2 * w + r;
    const float* srow = sc + ((size_t)(b * QL) + q0 + row) * KL;
    const int kb = l * 8;
    float v[8];
#pragma unroll
    for (int j = 0; j < 8; ++j)
      v[j] = (kb + j < vlen) ? srow[kb + j] : NEG_INF;
    float m = v[0];
#pragma unroll
    for (int j = 1; j < 8; ++j) m = fmaxf(m, v[j]);
#pragma unroll
    for (int off = 32; off >= 1; off >>= 1) m = fmaxf(m, __shfl_xor(m, off, 64));
    float s = 0.f;
#pragma unroll
    for (int j = 0; j < 8; ++j) { v[j] = __expf(v[j] - m); s += v[j]; }
#pragma unroll
    for (int off = 32; off >= 1; off >>= 1) s += __shfl_xor(s, off, 64);
    const float inv = fast_rcp(s);       // s >= 1 (max term contributes 1)
#pragma unroll
    for (int j = 0; j < 8; ++j) p_s[row][kb + j] = v[j] * inv;
  }
  __syncthreads();

  const int dl = t & 127, qg = t >> 7;
  const float* __restrict__ vb = value + (size_t)b * KL * DD + d0 + dl;
  float acc[4] = {0.f, 0.f, 0.f, 0.f};
  const int kmax = (vlen + 31) & ~31;    // p_s beyond vlen is exactly 0

  float va[16], vbuf[16];
#pragma unroll
  for (int j = 0; j < 16; ++j) va[j] = vb[(size_t)j * DD];

  for (int k = 0; k < kmax; k += 32) {
    const int k1 = k + 16;               // k1 <= kmax-16 < KL: always in range
#pragma unroll
    for (int j = 0; j < 16; ++j) vbuf[j] = vb[(size_t)(k1 + j) * DD];
#pragma unroll
    for (int g = 0; g < 4; ++g) {
#pragma unroll
      for (int q = 0; q < 4; ++q) {
        const float4 a = *reinterpret_cast<const float4*>(&p_s[qg * 4 + q][k + 4 * g]);
        acc[q] = fmaf(a.x, va[4 * g + 0], fmaf(a.y, va[4 * g + 1],
                 fmaf(a.z, va[4 * g + 2], fmaf(a.w, va[4 * g + 3], acc[q]))));
      }
    }
    const int k2 = (k + 32 < kmax) ? k + 32 : 0;   // clamped dummy prefetch
#pragma unroll
    for (int j = 0; j < 16; ++j) va[j] = vb[(size_t)(k2 + j) * DD];
#pragma unroll
    for (int g = 0; g < 4; ++g) {
#pragma unroll
      for (int q = 0; q < 4; ++q) {
        const float4 a = *reinterpret_cast<const float4*>(&p_s[qg * 4 + q][k1 + 4 * g]);
        acc[q] = fmaf(a.x, vbuf[4 * g + 0], fmaf(a.y, vbuf[4 * g + 1],
                 fmaf(a.z, vbuf[4 * g + 2], fmaf(a.w, vbuf[4 * g + 3], acc[q]))));
      }
    }
  }
#pragma unroll
  for (int q = 0; q < 4; ++q)
    out[((size_t)(b * QL) + q0 + qg * 4 + q) * DD + d0 + dl] = acc[q];
}

extern "C" void kernel_launch(void* const* d_in, const int* in_sizes, int n_in,
                              void* d_out, int out_size, void* d_ws, size_t ws_size,
                              hipStream_t stream) {
  const float* query     = (const float*)d_in[0];
  const float* key       = (const float*)d_in[1];
  const float* value     = (const float*)d_in[2];
  const int*   valid_len = (const int*)d_in[3];
  const float* Wq        = (const float*)d_in[4];
  const float* Wk        = (const float*)d_in[5];
  const float* v_w       = (const float*)d_in[6];
  float* out = (float*)d_out;

  float* qp  = (float*)d_ws;                        // B*QL*U floats (1 MB)
  float* kpN = qp + (size_t)Bsz * QL * UU;          // B*KL*U floats (4 MB)
  float* sc  = kpN + (size_t)Bsz * KL * UU;         // B*QL*KL floats (2 MB)

  const int proj_blocks = (Bsz * QL + Bsz * KL) / PR;      // 640
  proj_kernel<<<proj_blocks, 256, 0, stream>>>(query, key, Wq, Wk, valid_len,
                                               qp, kpN);

  const int score_blocks = Bsz * (QL / SQB) * (KL / SKB);  // 512
  scores_kernel<<<score_blocks, 256, 0, stream>>>(valid_len, v_w, qp, kpN, sc);

  const int pv_blocks = Bsz * (QL / SQB) * (DD / 128);     // 256
  softmax_pv_kernel<<<pv_blocks, 256, 0, stream>>>(value, valid_len, sc, out);
}

// Round 8
// 132.935 us; speedup vs baseline: 1.1068x; 1.1068x over previous
//
#include <hip/hip_runtime.h>
#include <hip/hip_bf16.h>

#ifndef __has_builtin
#define __has_builtin(x) 0
#endif

__device__ __forceinline__ float fast_exp2(float x) {
#if __has_builtin(__builtin_amdgcn_exp2f)
  return __builtin_amdgcn_exp2f(x);
#else
  return exp2f(x);
#endif
}
__device__ __forceinline__ float fast_rcp(float x) {
#if __has_builtin(__builtin_amdgcn_rcpf)
  return __builtin_amdgcn_rcpf(x);
#else
  return 1.0f / x;
#endif
}

constexpr int Bsz = 8, QL = 128, KL = 512, DD = 256, UU = 256;
constexpr int PR = 4;                    // rows per proj block (1280 blocks)
constexpr int DT = 8;                    // d-chunk in proj pipeline
constexpr int FQB = 2;                   // q rows per fused block
constexpr float NEG_INF = -1e6f;
constexpr float C2 = 2.885390081777927f; // 2*log2(e): exp2(C2*x) == exp(2x)

// ---------------------------------------------------------------------------
// Kernel 1: projections, pre-scaled by C2, natural layout:
//   qp [b][q][u], kpN[b][k][u]  (stores coalesced, lane = u).
// PR=4 rows/block -> 1280 blocks (5/CU, 20 waves/CU). Dual double-buffer:
// next tile's W (coalesced) AND rows (wave-uniform) are issued BEFORE the
// current tile's compute; the rotate's vmcnt wait lands after 64cy of FMA
// and is further hidden by 5 waves/SIMD interleave. Masked key blocks exit.
// ---------------------------------------------------------------------------
__global__ __launch_bounds__(256) void proj_kernel(
    const float* __restrict__ query, const float* __restrict__ key,
    const float* __restrict__ Wq, const float* __restrict__ Wk,
    const int* __restrict__ valid_len,
    float* __restrict__ qp, float* __restrict__ kpN)
{
  const int u   = threadIdx.x;
  const int blk = blockIdx.x;
  constexpr int QBLKS = Bsz * QL / PR;   // 256
  const bool isQ = blk < QBLKS;
  const int  m0  = isQ ? blk * PR : (blk - QBLKS) * PR;

  if (!isQ) {
    const int b = m0 / KL, k0 = m0 % KL;
    if (k0 >= valid_len[b]) return;      // masked rows never read downstream
  }
  const float* __restrict__ in = isQ ? query : key;
  const float* __restrict__ W  = isQ ? Wq : Wk;
  const float* r0 = in + (size_t)m0 * DD;

  float acc[PR];
#pragma unroll
  for (int r = 0; r < PR; ++r) acc[r] = 0.f;

  float  w_c[DT], w_n[DT];
  float4 r_c[PR][2], r_n[PR][2];

  // prologue: tile d=0
#pragma unroll
  for (int j = 0; j < DT; ++j) w_c[j] = W[j * UU + u];
#pragma unroll
  for (int r = 0; r < PR; ++r) {
    r_c[r][0] = *reinterpret_cast<const float4*>(r0 + r * DD);
    r_c[r][1] = *reinterpret_cast<const float4*>(r0 + r * DD + 4);
  }

  for (int d = 0; d < DD; d += DT) {
    const int dn = (d + DT < DD) ? d + DT : 0;   // clamped dummy on last
    // issue ALL next-tile loads first; they stay in flight during compute
#pragma unroll
    for (int j = 0; j < DT; ++j) w_n[j] = W[(dn + j) * UU + u];
#pragma unroll
    for (int r = 0; r < PR; ++r) {
      r_n[r][0] = *reinterpret_cast<const float4*>(r0 + r * DD + dn);
      r_n[r][1] = *reinterpret_cast<const float4*>(r0 + r * DD + dn + 4);
    }
    // compute on current tile (registers only — no waits here)
#pragma unroll
    for (int r = 0; r < PR; ++r) {
      float a = acc[r];
      a = fmaf(r_c[r][0].x, w_c[0], a);
      a = fmaf(r_c[r][0].y, w_c[1], a);
      a = fmaf(r_c[r][0].z, w_c[2], a);
      a = fmaf(r_c[r][0].w, w_c[3], a);
      a = fmaf(r_c[r][1].x, w_c[4], a);
      a = fmaf(r_c[r][1].y, w_c[5], a);
      a = fmaf(r_c[r][1].z, w_c[6], a);
      a = fmaf(r_c[r][1].w, w_c[7], a);
      acc[r] = a;
    }
#pragma unroll
    for (int j = 0; j < DT; ++j) w_c[j] = w_n[j];
#pragma unroll
    for (int r = 0; r < PR; ++r) { r_c[r][0] = r_n[r][0]; r_c[r][1] = r_n[r][1]; }
  }

  float* o = (isQ ? qp : kpN) + (size_t)m0 * UU + u;   // natural [row][u]
#pragma unroll
  for (int r = 0; r < PR; ++r) o[(size_t)r * UU] = acc[r] * C2;
}

// ---------------------------------------------------------------------------
// Kernel 2: FUSED scores + masked softmax + PV for (b, 2 q-rows).
// 512 blocks (2/CU), 256 threads. Scores never touch global: they live in
// LDS (sps[k] = float2(row0,row1)). PV uses unnormalized exp weights and
// scales the final output by 1/sum (saves a normalize pass).
//   Scores: wave w owns k-strip [128w,128w+128); lane l owns k = 2l(+1) of
//   the strip x 2 q rows -> 4 accs, 8 trans insts per u (dense). kpN [b][k][u]
//   gives each lane contiguous u-runs (2 float4 per 8-u tile, prefetched).
//   Fully-masked strips skip the u-loop and just write NEG_INF.
//   Softmax: waves 0/1 reduce k-halves for both rows at once (float2 math).
//   PV: thread = d; sps reads are wave-uniform broadcasts; value loads
//   coalesced, 16-deep prefetch; p beyond vlen is exactly 0.
// ---------------------------------------------------------------------------
__global__ __launch_bounds__(256) void fused_attn_kernel(
    const float* __restrict__ value, const int* __restrict__ valid_len,
    const float* __restrict__ v_w, const float* __restrict__ qp,
    const float* __restrict__ kpN, float* __restrict__ out)
{
  __shared__ __align__(16) float2 sps[KL];   // 4 KB: scores -> exp weights
  __shared__ float2 qpq_s[UU];               // 2 KB: (q0,q1) per u
  __shared__ float  w2_s[UU];                // 1 KB
  __shared__ float2 red2[4];                 // [0,1]=max halves, [2,3]=sum halves

  const int t   = threadIdx.x;
  const int blk = blockIdx.x;
  const int b   = blk & 7;                   // batch fastest: mixed vlen per CU
  const int q0  = (blk >> 3) * FQB;
  const int vlen = valid_len[b];
  const int w = t >> 6, l = t & 63;

  // ---- stage qp rows (as float2 per u) + 2*v_w ----
  w2_s[t] = 2.0f * v_w[t];
  qpq_s[t] = make_float2(qp[(size_t)(b * QL + q0) * UU + t],
                         qp[(size_t)(b * QL + q0 + 1) * UU + t]);
  __syncthreads();

  // ---- scores for wave strip ----
  const int kb = 128 * w + 2 * l;            // lane's first k
  float a00 = 0.f, a01 = 0.f, a10 = 0.f, a11 = 0.f;  // [row][kslot]

  if (128 * w < vlen) {
    const float* __restrict__ kcol = kpN + ((size_t)(b * KL) + kb) * UU;
    float c0[8], c1[8], n0[8], n1[8];
    *reinterpret_cast<float4*>(&c0[0]) = *reinterpret_cast<const float4*>(kcol);
    *reinterpret_cast<float4*>(&c0[4]) = *reinterpret_cast<const float4*>(kcol + 4);
    *reinterpret_cast<float4*>(&c1[0]) = *reinterpret_cast<const float4*>(kcol + UU);
    *reinterpret_cast<float4*>(&c1[4]) = *reinterpret_cast<const float4*>(kcol + UU + 4);

    for (int u0 = 0; u0 < UU; u0 += 8) {
      const int un = (u0 + 8 < UU) ? u0 + 8 : 0;   // clamped dummy on last
      *reinterpret_cast<float4*>(&n0[0]) =
          *reinterpret_cast<const float4*>(kcol + un);
      *reinterpret_cast<float4*>(&n0[4]) =
          *reinterpret_cast<const float4*>(kcol + un + 4);
      *reinterpret_cast<float4*>(&n1[0]) =
          *reinterpret_cast<const float4*>(kcol + UU + un);
      *reinterpret_cast<float4*>(&n1[4]) =
          *reinterpret_cast<const float4*>(kcol + UU + un + 4);
#pragma unroll
      for (int j = 0; j < 8; ++j) {
        const float2 qv = qpq_s[u0 + j];     // ds_read_b64 broadcast
        const float  w2 = w2_s[u0 + j];
        const float e00 = fast_exp2(qv.x + c0[j]);
        const float e01 = fast_exp2(qv.x + c1[j]);
        const float e10 = fast_exp2(qv.y + c0[j]);
        const float e11 = fast_exp2(qv.y + c1[j]);
        a00 = fmaf(w2, fast_rcp(1.0f + e00), a00);
        a01 = fmaf(w2, fast_rcp(1.0f + e01), a01);
        a10 = fmaf(w2, fast_rcp(1.0f + e10), a10);
        a11 = fmaf(w2, fast_rcp(1.0f + e11), a11);
      }
#pragma unroll
      for (int j = 0; j < 8; ++j) { c0[j] = n0[j]; c1[j] = n1[j]; }
    }
  }
  // write scores (softmax shift-invariance: constant sum(v_w) dropped)
  {
    float4 sv;
    sv.x = (kb     < vlen) ? -a00 : NEG_INF;   // sps[kb].x   (row 0)
    sv.y = (kb     < vlen) ? -a10 : NEG_INF;   // sps[kb].y   (row 1)
    sv.z = (kb + 1 < vlen) ? -a01 : NEG_INF;   // sps[kb+1].x
    sv.w = (kb + 1 < vlen) ? -a11 : NEG_INF;   // sps[kb+1].y
    *reinterpret_cast<float4*>(&sps[kb]) = sv;
  }
  __syncthreads();

  // ---- softmax (both rows at once, float2 math); waves 0,1 own k-halves ----
  float4 sa, sb;
  if (w < 2) {
    const int base = 256 * w + 4 * l;        // 4 consecutive k
    sa = *reinterpret_cast<const float4*>(&sps[base]);      // k, k+1
    sb = *reinterpret_cast<const float4*>(&sps[base + 2]);  // k+2, k+3
    float mx0 = fmaxf(fmaxf(sa.x, sa.z), fmaxf(sb.x, sb.z));
    float mx1 = fmaxf(fmaxf(sa.y, sa.w), fmaxf(sb.y, sb.w));
#pragma unroll
    for (int off = 32; off >= 1; off >>= 1) {
      mx0 = fmaxf(mx0, __shfl_xor(mx0, off, 64));
      mx1 = fmaxf(mx1, __shfl_xor(mx1, off, 64));
    }
    if (l == 0) red2[w] = make_float2(mx0, mx1);
  }
  __syncthreads();
  const float m0r = fmaxf(red2[0].x, red2[1].x);
  const float m1r = fmaxf(red2[0].y, red2[1].y);
  if (w < 2) {
    const int base = 256 * w + 4 * l;
    sa.x = __expf(sa.x - m0r);  sa.y = __expf(sa.y - m1r);
    sa.z = __expf(sa.z - m0r);  sa.w = __expf(sa.w - m1r);
    sb.x = __expf(sb.x - m0r);  sb.y = __expf(sb.y - m1r);
    sb.z = __expf(sb.z - m0r);  sb.w = __expf(sb.w - m1r);
    *reinterpret_cast<float4*>(&sps[base])     = sa;
    *reinterpret_cast<float4*>(&sps[base + 2]) = sb;
    float s0 = sa.x + sa.z + sb.x + sb.z;
    float s1 = sa.y + sa.w + sb.y + sb.w;
#pragma unroll
    for (int off = 32; off >= 1; off >>= 1) {
      s0 += __shfl_xor(s0, off, 64);
      s1 += __shfl_xor(s1, off, 64);
    }
    if (l == 0) red2[2 + w] = make_float2(s0, s1);
  }
  __syncthreads();
  const float inv0 = fast_rcp(red2[2].x + red2[3].x);  // sums >= 1
  const float inv1 = fast_rcp(red2[2].y + red2[3].y);

  // ---- PV: thread = d; unnormalized weights, scale at the end ----
  const float* __restrict__ vb = value + (size_t)b * KL * DD + t;
  float o0 = 0.f, o1 = 0.f;
  const int kmax = (vlen + 15) & ~15;        // sps beyond vlen is exactly 0

  float vc[16], vn[16];
#pragma unroll
  for (int j = 0; j < 16; ++j) vc[j] = vb[(size_t)j * DD];
  for (int k = 0; k < kmax; k += 16) {
    const int kn = (k + 16 < kmax) ? k + 16 : 0;
#pragma unroll
    for (int j = 0; j < 16; ++j) vn[j] = vb[(size_t)(kn + j) * DD];
#pragma unroll
    for (int j = 0; j < 16; ++j) {
      const float2 p = sps[k + j];           // broadcast
      o0 = fmaf(p.x, vc[j], o0);
      o1 = fmaf(p.y, vc[j], o1);
    }
#pragma unroll
    for (int j = 0; j < 16; ++j) vc[j] = vn[j];
  }
  out[(size_t)(b * QL + q0) * DD + t]     = o0 * inv0;
  out[(size_t)(b * QL + q0 + 1) * DD + t] = o1 * inv1;
}

extern "C" void kernel_launch(void* const* d_in, const int* in_sizes, int n_in,
                              void* d_out, int out_size, void* d_ws, size_t ws_size,
                              hipStream_t stream) {
  const float* query     = (const float*)d_in[0];
  const float* key       = (const float*)d_in[1];
  const float* value     = (const float*)d_in[2];
  const int*   valid_len = (const int*)d_in[3];
  const float* Wq        = (const float*)d_in[4];
  const float* Wk        = (const float*)d_in[5];
  const float* v_w       = (const float*)d_in[6];
  float* out = (float*)d_out;

  float* qp  = (float*)d_ws;                        // B*QL*U floats (1 MB)
  float* kpN = qp + (size_t)Bsz * QL * UU;          // B*KL*U floats (4 MB)

  const int proj_blocks = (Bsz * QL + Bsz * KL) / PR;   // 1280
  proj_kernel<<<proj_blocks, 256, 0, stream>>>(query, key, Wq, Wk, valid_len,
                                               qp, kpN);

  const int fused_blocks = Bsz * (QL / FQB);            // 512
  fused_attn_kernel<<<fused_blocks, 256, 0, stream>>>(value, valid_len, v_w,
                                                      qp, kpN, out);
}